// Round 4
// baseline (483.329 us; speedup 1.0000x reference)
//
#include <hip/hip_runtime.h>
#include <cstdint>
#include <cstddef>

#define N_NODES 100000
#define N_EDGES 3200000
#define N_FEAT  512
#define HIDDEN  16
#define NBUCK   ((N_NODES + 255) / 256)   // 391 buckets of 256 rows
#define BCAP    10240                     // slots/bucket; mean 8184, +22 sigma
#define CHUNK   4096                      // edges per binscatter block

// ---------------------------------------------------------------------------
// async global -> LDS, 16B per lane. LDS dest is wave-uniform base + lane*16.
__device__ __forceinline__ void gload_lds16(const float* g, void* lds) {
  __builtin_amdgcn_global_load_lds(
      (const __attribute__((address_space(1))) void*)g,
      (__attribute__((address_space(3))) void*)lds, 16, 0, 0);
}

// ---------------------------------------------------------------------------
// Kernel 1: xw[r][c] = sum_k x[r][k] * W1[k][c]     (N_FEAT=512, 16 outputs)
// 1-wave blocks, lane = row, 64 rows/block, double-buffered global_load_lds
// with counted vmcnt(8); XOR-swizzled LDS (inverse swizzle on global source).
__global__ __launch_bounds__(64)
void k_gemm1(const float* __restrict__ x, const float* __restrict__ W1,
             float* __restrict__ xw) {
  __shared__ float4 xs[2][512];          // 2 x 8KB
  const int l = threadIdx.x;
  const int rbase = blockIdx.x * 64;

  float acc[16];
#pragma unroll
  for (int c = 0; c < 16; ++c) acc[c] = 0.f;

  const int srow = l >> 3;
  const int sq   = l & 7;
  const int kq   = sq ^ srow;            // inverse swizzle on source

  auto STAGE = [&](int b, int ck) {
    const int kb = ck * 32;
#pragma unroll
    for (int i = 0; i < 8; ++i) {
      int grow = rbase + i * 8 + srow;
      if (grow >= N_NODES) grow = N_NODES - 1;
      gload_lds16(x + (size_t)grow * N_FEAT + kb + kq * 4, &xs[b][i * 64]);
    }
  };

  auto COMPUTE = [&](int b, int ck) {
    const int kb = ck * 32;
#pragma unroll
    for (int q = 0; q < 8; ++q) {
      float4 xv = xs[b][l * 8 + (q ^ (l & 7))];
      float xe[4] = {xv.x, xv.y, xv.z, xv.w};
#pragma unroll
      for (int j = 0; j < 4; ++j) {
        const float* wrow = W1 + (size_t)(kb + q * 4 + j) * 16;
#pragma unroll
        for (int c = 0; c < 16; ++c)
          acc[c] = fmaf(xe[j], wrow[c], acc[c]);
      }
    }
  };

  STAGE(0, 0);
#pragma unroll 1
  for (int ck = 0; ck < 16; ++ck) {
    const int b = ck & 1;
    if (ck + 1 < 16) {
      STAGE(b ^ 1, ck + 1);
      asm volatile("s_waitcnt vmcnt(8)" ::: "memory");
    } else {
      asm volatile("s_waitcnt vmcnt(0)" ::: "memory");
    }
    COMPUTE(b, ck);
  }

  const int grow = rbase + l;
  if (grow < N_NODES) {
    float4* o = (float4*)(xw + (size_t)grow * 16);
    o[0] = make_float4(acc[0],  acc[1],  acc[2],  acc[3]);
    o[1] = make_float4(acc[4],  acc[5],  acc[6],  acc[7]);
    o[2] = make_float4(acc[8],  acc[9],  acc[10], acc[11]);
    o[3] = make_float4(acc[12], acc[13], acc[14], acc[15]);
  }
}

// ---------------------------------------------------------------------------
// Bin edges into 391 buckets of 256 rows. Per 4096-edge block: LDS stash +
// LDS histogram, ~391 block-aggregated global atomics to reserve ranges,
// then atomic-free-ish scatter of packed {col | row8<<20, val_bits}.
__global__ __launch_bounds__(256)
void k_binscatter(const int* __restrict__ rows, const int* __restrict__ cols,
                  const float* __restrict__ vals, int* __restrict__ cursor,
                  int2* __restrict__ binned) {
  __shared__ int2 stash[CHUNK];                 // 32 KB
  __shared__ unsigned short sbuck[CHUNK];       // 8 KB
  __shared__ int hist[NBUCK];
  __shared__ int base[NBUCK];
  const int t = threadIdx.x;
  const int e0 = blockIdx.x * CHUNK;
  const int nv = (N_EDGES - e0 < CHUNK) ? (N_EDGES - e0) : CHUNK;

  for (int b = t; b < NBUCK; b += 256) hist[b] = 0;
  __syncthreads();

#pragma unroll
  for (int i = 0; i < CHUNK / 256; ++i) {
    const int idx = i * 256 + t;
    if (idx < nv) {
      const int e = e0 + idx;
      const int r = rows[e], c = cols[e];
      const float v = vals[e];
      const int b = r >> 8;
      stash[idx] = make_int2(c | ((r & 255) << 20), __float_as_int(v));
      sbuck[idx] = (unsigned short)b;
      atomicAdd(&hist[b], 1);                   // LDS atomic
    }
  }
  __syncthreads();

  for (int b = t; b < NBUCK; b += 256) {
    const int h = hist[b];
    base[b] = (h > 0) ? atomicAdd(&cursor[b], h) : 0;   // global, aggregated
    hist[b] = 0;                                         // reuse as rank ctr
  }
  __syncthreads();

#pragma unroll
  for (int i = 0; i < CHUNK / 256; ++i) {
    const int idx = i * 256 + t;
    if (idx < nv) {
      const int b = sbuck[idx];
      const int off = base[b] + atomicAdd(&hist[b], 1);  // LDS atomic
      if (off < BCAP) binned[(size_t)b * BCAP + off] = stash[idx];
    }
  }
}

// ---------------------------------------------------------------------------
// Layer-1 aggregate: per bucket, LDS acc[256][17] via ds_add_f32, fused
// bias + relu + (.) @ W2 -> hw1.  16 lanes per edge, 2x unrolled chains.
__global__ __launch_bounds__(512)
void k_agg1(const int2* __restrict__ binned, const int* __restrict__ cursor,
            const float* __restrict__ xw, const float* __restrict__ b1,
            const float* __restrict__ W2, float* __restrict__ hw1) {
  __shared__ float acc[256][17];                // padded: conflict-light
  const int t = threadIdx.x;
  const int b = blockIdx.x;
  const int lane16 = t & 15;
  const int g = t >> 4;                         // 0..31 edge groups

  for (int i = t; i < 256 * 17; i += 512) ((float*)acc)[i] = 0.f;
  __syncthreads();

  const int raw = cursor[b];
  const int cnt = raw < BCAP ? raw : BCAP;
  const int2* ep = binned + (size_t)b * BCAP;

  int j = g;
  for (; j + 32 < cnt; j += 64) {               // 2 independent chains
    const int2 ea = ep[j], eb = ep[j + 32];
    const float va = __int_as_float(ea.y) * xw[(size_t)(ea.x & 0xFFFFF) * 16 + lane16];
    const float vb = __int_as_float(eb.y) * xw[(size_t)(eb.x & 0xFFFFF) * 16 + lane16];
    atomicAdd(&acc[ea.x >> 20][lane16], va);
    atomicAdd(&acc[eb.x >> 20][lane16], vb);
  }
  for (; j < cnt; j += 32) {
    const int2 ea = ep[j];
    const float va = __int_as_float(ea.y) * xw[(size_t)(ea.x & 0xFFFFF) * 16 + lane16];
    atomicAdd(&acc[ea.x >> 20][lane16], va);
  }
  __syncthreads();

  if (t < 256) {
    const int r = b * 256 + t;
    if (r < N_NODES) {
      float s = 0.f;
#pragma unroll
      for (int c = 0; c < 16; ++c)
        s = fmaf(fmaxf(acc[t][c] + b1[c], 0.f), W2[c], s);
      hw1[r] = s;
    }
  }
}

// ---------------------------------------------------------------------------
// Layer-2 aggregate: per bucket, scalar LDS acc + sigmoid -> out.
__global__ __launch_bounds__(512)
void k_agg2(const int2* __restrict__ binned, const int* __restrict__ cursor,
            const float* __restrict__ hw1, const float* __restrict__ b2,
            float* __restrict__ out) {
  __shared__ float acc2[256];
  const int t = threadIdx.x;
  const int b = blockIdx.x;
  if (t < 256) acc2[t] = 0.f;
  __syncthreads();

  const int raw = cursor[b];
  const int cnt = raw < BCAP ? raw : BCAP;
  const int2* ep = binned + (size_t)b * BCAP;

  int j = t;
  for (; j + 512 < cnt; j += 1024) {            // 2 independent chains
    const int2 ea = ep[j], eb = ep[j + 512];
    const float va = __int_as_float(ea.y) * hw1[ea.x & 0xFFFFF];
    const float vb = __int_as_float(eb.y) * hw1[eb.x & 0xFFFFF];
    atomicAdd(&acc2[ea.x >> 20], va);
    atomicAdd(&acc2[eb.x >> 20], vb);
  }
  for (; j < cnt; j += 512) {
    const int2 ea = ep[j];
    atomicAdd(&acc2[ea.x >> 20], __int_as_float(ea.y) * hw1[ea.x & 0xFFFFF]);
  }
  __syncthreads();

  if (t < 256) {
    const int r = b * 256 + t;
    if (r < N_NODES) out[r] = 1.f / (1.f + expf(-(acc2[t] + b2[0])));
  }
}

// ---------------------------------------------------------------------------
extern "C" void kernel_launch(void* const* d_in, const int* in_sizes, int n_in,
                              void* d_out, int out_size, void* d_ws, size_t ws_size,
                              hipStream_t stream) {
  const float* x    = (const float*)d_in[0];
  const float* vals = (const float*)d_in[1];
  const float* W1   = (const float*)d_in[2];
  const float* b1   = (const float*)d_in[3];
  const float* W2   = (const float*)d_in[4];
  const float* b2   = (const float*)d_in[5];
  const int*   rows = (const int*)d_in[6];
  const int*   cols = (const int*)d_in[7];
  float* out = (float*)d_out;

  // workspace: xw[N*16]f (6.4MB) | binned[NBUCK*BCAP]int2 (32.03MB) |
  //            cursor[NBUCK]i | hw1[N]f   -> ~38.9 MB total
  char* w = (char*)d_ws;
  float* xw     = (float*)w;   w += (size_t)N_NODES * 16 * 4;
  int2*  binned = (int2*)w;    w += (size_t)NBUCK * BCAP * 8;
  int*   cursor = (int*)w;     w += (size_t)((NBUCK + 3) & ~3) * 4;
  float* hw1    = (float*)w;

  hipMemsetAsync(cursor, 0, (size_t)NBUCK * 4, stream);

  k_gemm1     <<<(N_NODES + 63) / 64,       64,  0, stream>>>(x, W1, xw);
  k_binscatter<<<(N_EDGES + CHUNK - 1) / CHUNK, 256, 0, stream>>>(rows, cols, vals,
                                                                  cursor, binned);
  k_agg1      <<<NBUCK,                     512, 0, stream>>>(binned, cursor, xw,
                                                              b1, W2, hw1);
  k_agg2      <<<NBUCK,                     512, 0, stream>>>(binned, cursor, hw1,
                                                              b2, out);
}

// Round 5
// 236.653 us; speedup vs baseline: 2.0424x; 2.0424x over previous
//
#include <hip/hip_runtime.h>
#include <cstdint>
#include <cstddef>

#define N_NODES 100000
#define N_EDGES 3200000
#define N_FEAT  512
#define HIDDEN  16
#define NBUCK   ((N_NODES + 127) / 128)   // 782 buckets of 128 rows
#define BCAP    5120                      // slots/bucket; mean 4096, +16 sigma
#define CHUNK   4096                      // edges per binscatter block

// ---------------------------------------------------------------------------
// async global -> LDS, 16B per lane. LDS dest is wave-uniform base + lane*16.
__device__ __forceinline__ void gload_lds16(const float* g, void* lds) {
  __builtin_amdgcn_global_load_lds(
      (const __attribute__((address_space(1))) void*)g,
      (__attribute__((address_space(3))) void*)lds, 16, 0, 0);
}

// ---------------------------------------------------------------------------
// Kernel 1: xw[r][c] = sum_k x[r][k] * W1[k][c]     (N_FEAT=512, 16 outputs)
// 1-wave blocks, lane = row, 64 rows/block, double-buffered global_load_lds
// with counted vmcnt(8); XOR-swizzled LDS (inverse swizzle on global source).
__global__ __launch_bounds__(64)
void k_gemm1(const float* __restrict__ x, const float* __restrict__ W1,
             float* __restrict__ xw) {
  __shared__ float4 xs[2][512];          // 2 x 8KB
  const int l = threadIdx.x;
  const int rbase = blockIdx.x * 64;

  float acc[16];
#pragma unroll
  for (int c = 0; c < 16; ++c) acc[c] = 0.f;

  const int srow = l >> 3;
  const int sq   = l & 7;
  const int kq   = sq ^ srow;            // inverse swizzle on source

  auto STAGE = [&](int b, int ck) {
    const int kb = ck * 32;
#pragma unroll
    for (int i = 0; i < 8; ++i) {
      int grow = rbase + i * 8 + srow;
      if (grow >= N_NODES) grow = N_NODES - 1;
      gload_lds16(x + (size_t)grow * N_FEAT + kb + kq * 4, &xs[b][i * 64]);
    }
  };

  auto COMPUTE = [&](int b, int ck) {
    const int kb = ck * 32;
#pragma unroll
    for (int q = 0; q < 8; ++q) {
      float4 xv = xs[b][l * 8 + (q ^ (l & 7))];
      float xe[4] = {xv.x, xv.y, xv.z, xv.w};
#pragma unroll
      for (int j = 0; j < 4; ++j) {
        const float* wrow = W1 + (size_t)(kb + q * 4 + j) * 16;
#pragma unroll
        for (int c = 0; c < 16; ++c)
          acc[c] = fmaf(xe[j], wrow[c], acc[c]);
      }
    }
  };

  STAGE(0, 0);
#pragma unroll 1
  for (int ck = 0; ck < 16; ++ck) {
    const int b = ck & 1;
    if (ck + 1 < 16) {
      STAGE(b ^ 1, ck + 1);
      asm volatile("s_waitcnt vmcnt(8)" ::: "memory");
    } else {
      asm volatile("s_waitcnt vmcnt(0)" ::: "memory");
    }
    COMPUTE(b, ck);
  }

  const int grow = rbase + l;
  if (grow < N_NODES) {
    float4* o = (float4*)(xw + (size_t)grow * 16);
    o[0] = make_float4(acc[0],  acc[1],  acc[2],  acc[3]);
    o[1] = make_float4(acc[4],  acc[5],  acc[6],  acc[7]);
    o[2] = make_float4(acc[8],  acc[9],  acc[10], acc[11]);
    o[3] = make_float4(acc[12], acc[13], acc[14], acc[15]);
  }
}

// ---------------------------------------------------------------------------
// Bucket edges by row>>7 (782 buckets of 128 rows). Per 4096-edge block:
// LDS stash + LDS histogram, ~780 block-aggregated global cursor atomics,
// then scatter of packed {col | (row&127)<<20, val_bits} into bucket slots.
__global__ __launch_bounds__(256)
void k_binscatter(const int* __restrict__ rows, const int* __restrict__ cols,
                  const float* __restrict__ vals, int* __restrict__ cursor,
                  int2* __restrict__ binned) {
  __shared__ int2 stash[CHUNK];                 // 32 KB
  __shared__ unsigned short sbuck[CHUNK];       // 8 KB
  __shared__ int hist[NBUCK];                   // 3.1 KB
  __shared__ int base[NBUCK];                   // 3.1 KB
  const int t = threadIdx.x;
  const int e0 = blockIdx.x * CHUNK;
  const int nv = (N_EDGES - e0 < CHUNK) ? (N_EDGES - e0) : CHUNK;

  for (int b = t; b < NBUCK; b += 256) hist[b] = 0;
  __syncthreads();

#pragma unroll
  for (int i = 0; i < CHUNK / 256; ++i) {
    const int idx = i * 256 + t;
    if (idx < nv) {
      const int e = e0 + idx;
      const int r = rows[e], c = cols[e];
      const float v = vals[e];
      const int b = r >> 7;
      stash[idx] = make_int2(c | ((r & 127) << 20), __float_as_int(v));
      sbuck[idx] = (unsigned short)b;
      atomicAdd(&hist[b], 1);                   // LDS atomic
    }
  }
  __syncthreads();

  for (int b = t; b < NBUCK; b += 256) {
    const int h = hist[b];
    base[b] = (h > 0) ? atomicAdd(&cursor[b], h) : 0;   // global, aggregated
    hist[b] = 0;                                         // reuse as rank ctr
  }
  __syncthreads();

#pragma unroll
  for (int i = 0; i < CHUNK / 256; ++i) {
    const int idx = i * 256 + t;
    if (idx < nv) {
      const int b = sbuck[idx];
      const int off = base[b] + atomicAdd(&hist[b], 1);  // LDS atomic
      if (off < BCAP) binned[(size_t)b * BCAP + off] = stash[idx];
    }
  }
}

// ---------------------------------------------------------------------------
// Per-bucket in-place counting sort -> bucket-local CSR + row_beg/row_end.
// All LDS: stash + rank via LDS atomics + 128-wide scan. Zero global atomics.
__global__ __launch_bounds__(256)
void k_localcsr(int2* __restrict__ binned, const int* __restrict__ cursor,
                int* __restrict__ row_beg, int* __restrict__ row_end) {
  __shared__ int2 stash[BCAP];                  // 40 KB
  __shared__ unsigned short rk[BCAP];           // 10 KB
  __shared__ int hist[128];
  __shared__ int pfx[128];
  const int t = threadIdx.x;
  const int b = blockIdx.x;
  const int raw = cursor[b];
  const int cnt = raw < BCAP ? raw : BCAP;
  int2* ep = binned + (size_t)b * BCAP;

  if (t < 128) hist[t] = 0;
  __syncthreads();

  for (int i = t; i < cnt; i += 256) {
    const int2 e = ep[i];
    stash[i] = e;
    rk[i] = (unsigned short)atomicAdd(&hist[(e.x >> 20) & 127], 1);
  }
  __syncthreads();

  if (t < 128) pfx[t] = hist[t];
  __syncthreads();
#pragma unroll
  for (int off = 1; off < 128; off <<= 1) {     // inclusive Hillis-Steele
    int add = (t >= off && t < 128) ? pfx[t - off] : 0;
    __syncthreads();
    if (t < 128) pfx[t] += add;
    __syncthreads();
  }

  if (t < 128) {
    const int r = b * 128 + t;
    if (r < N_NODES) {
      const int beg = b * BCAP + pfx[t] - hist[t];      // exclusive prefix
      row_beg[r] = beg;
      row_end[r] = beg + hist[t];
    }
  }
  __syncthreads();

  for (int i = t; i < cnt; i += 256) {
    const int2 e = stash[i];
    const int row = (e.x >> 20) & 127;
    ep[pfx[row] - hist[row] + (int)rk[i]] = e;
  }
}

// ---------------------------------------------------------------------------
// Fused layer-1 tail: gather-SPMM + bias + relu + (.) @ W2 -> hw1[r].
// 16 lanes per row (lane = hidden channel), 16 rows per 256-thread block.
__global__ __launch_bounds__(256)
void k_fused1(const int2* __restrict__ binned, const int* __restrict__ row_beg,
              const int* __restrict__ row_end, const float* __restrict__ xw,
              const float* __restrict__ b1, const float* __restrict__ W2,
              float* __restrict__ hw1) {
  const int t = threadIdx.x;
  const int lane16 = t & 15;
  const int r = blockIdx.x * 16 + (t >> 4);
  if (r >= N_NODES) return;
  const int s = row_beg[r], e = row_end[r];
  float a0 = 0.f, a1 = 0.f;
  int i = s;
  for (; i + 1 < e; i += 2) {                        // 2 independent chains
    int2 ea = binned[i], eb = binned[i + 1];
    a0 = fmaf(__int_as_float(ea.y), xw[(size_t)(ea.x & 0xFFFFF) * 16 + lane16], a0);
    a1 = fmaf(__int_as_float(eb.y), xw[(size_t)(eb.x & 0xFFFFF) * 16 + lane16], a1);
  }
  if (i < e) {
    int2 ea = binned[i];
    a0 = fmaf(__int_as_float(ea.y), xw[(size_t)(ea.x & 0xFFFFF) * 16 + lane16], a0);
  }
  float h = fmaxf(a0 + a1 + b1[lane16], 0.f);
  float p = h * W2[lane16];
#pragma unroll
  for (int m = 8; m >= 1; m >>= 1) p += __shfl_xor(p, m, 16);
  if (lane16 == 0) hw1[r] = p;
}

// ---------------------------------------------------------------------------
// Fused layer-2 tail: gather-SPMM on scalars + bias + sigmoid -> out[r].
__global__ __launch_bounds__(256)
void k_fused2(const int2* __restrict__ binned, const int* __restrict__ row_beg,
              const int* __restrict__ row_end, const float* __restrict__ hw1,
              const float* __restrict__ b2, float* __restrict__ out) {
  const int t = threadIdx.x;
  const int lane16 = t & 15;
  const int r = blockIdx.x * 16 + (t >> 4);
  if (r >= N_NODES) return;
  const int s = row_beg[r], e = row_end[r];
  float acc = 0.f;
  for (int i = s + lane16; i < e; i += 16) {
    int2 ev = binned[i];
    acc = fmaf(__int_as_float(ev.y), hw1[ev.x & 0xFFFFF], acc);
  }
#pragma unroll
  for (int m = 8; m >= 1; m >>= 1) acc += __shfl_xor(acc, m, 16);
  if (lane16 == 0) out[r] = 1.f / (1.f + expf(-(acc + b2[0])));
}

// ---------------------------------------------------------------------------
extern "C" void kernel_launch(void* const* d_in, const int* in_sizes, int n_in,
                              void* d_out, int out_size, void* d_ws, size_t ws_size,
                              hipStream_t stream) {
  const float* x    = (const float*)d_in[0];
  const float* vals = (const float*)d_in[1];
  const float* W1   = (const float*)d_in[2];
  const float* b1   = (const float*)d_in[3];
  const float* W2   = (const float*)d_in[4];
  const float* b2   = (const float*)d_in[5];
  const int*   rows = (const int*)d_in[6];
  const int*   cols = (const int*)d_in[7];
  float* out = (float*)d_out;

  // workspace: xw[N*16]f (6.4MB) | binned[NBUCK*BCAP]int2 (32.0MB) |
  //            cursor[NBUCK]i | row_beg[N]i | row_end[N]i | hw1[N]f  ~39.7MB
  char* w = (char*)d_ws;
  float* xw      = (float*)w;  w += (size_t)N_NODES * 16 * 4;
  int2*  binned  = (int2*)w;   w += (size_t)NBUCK * BCAP * 8;
  int*   cursor  = (int*)w;    w += (size_t)((NBUCK + 3) & ~3) * 4;
  int*   row_beg = (int*)w;    w += (size_t)N_NODES * 4;
  int*   row_end = (int*)w;    w += (size_t)N_NODES * 4;
  float* hw1     = (float*)w;

  hipMemsetAsync(cursor, 0, (size_t)NBUCK * 4, stream);

  k_gemm1     <<<(N_NODES + 63) / 64,           64,  0, stream>>>(x, W1, xw);
  k_binscatter<<<(N_EDGES + CHUNK - 1) / CHUNK, 256, 0, stream>>>(rows, cols, vals,
                                                                  cursor, binned);
  k_localcsr  <<<NBUCK,                         256, 0, stream>>>(binned, cursor,
                                                                  row_beg, row_end);
  k_fused1    <<<(N_NODES + 15) / 16,           256, 0, stream>>>(binned, row_beg,
                                                                  row_end, xw, b1,
                                                                  W2, hw1);
  k_fused2    <<<(N_NODES + 15) / 16,           256, 0, stream>>>(binned, row_beg,
                                                                  row_end, hw1,
                                                                  b2, out);
}